// Round 4
// baseline (270.973 us; speedup 1.0000x reference)
//
#include <hip/hip_runtime.h>
#include <hip/hip_bf16.h>

#define C_IMG   3
#define H_MAX   512
#define W_MAX   512
#define W_PAD   513   // stored row stride (W_max + 1, last col holds h/w)
#define OUT_H   224
#define OUT_W   224
#define OW_O    (OUT_W / 8)   // 28 octets per row
#define RESIZE_TO 256.0f

__global__ __launch_bounds__(256) void centercrop_kernel(
    const float* __restrict__ x, float* __restrict__ out, int total_octets)
{
    int idx = blockIdx.x * blockDim.x + threadIdx.x;
    if (idx >= total_octets) return;

    int q   = idx % OW_O;          // which group of 8 output columns
    int t   = idx / OW_O;
    int oy  = t % OUT_H;
    t      /= OUT_H;
    int c   = t % C_IMG;
    int b   = t / C_IMG;
    int ox0 = q * 8;

    const size_t img_stride = (size_t)H_MAX * W_PAD;       // per-channel elems
    const float* base = x + (size_t)b * C_IMG * img_stride;

    // h at [b,0,0,512], w at [b,1,0,512]
    float h = base[512];
    float w = base[img_stride + 512];

    float min_dim = fminf(h, w);
    float scale   = RESIZE_TO / min_dim;
    float h_res   = rintf(h * scale);          // jnp.round = half-even
    float w_res   = rintf(w * scale);
    float top     = rintf((h_res - (float)OUT_H) / 2.0f);
    float left    = rintf((w_res - (float)OUT_W) / 2.0f);

    // ---- per-row (once per thread, exact reference op order) ----
    float ysf   = (float)oy + top;
    float src_y = (ysf + 0.5f) * h / h_res - 0.5f;
    src_y = fminf(fmaxf(src_y, 0.0f), h - 1.0f);
    float y0f = floorf(src_y);
    float wy  = src_y - y0f;

    int hi = (int)h - 1;
    int wi = (int)w - 1;
    int y0 = min(max(min(max((int)y0f, 0), hi), 0), H_MAX - 1);
    int y1 = min(max(min(y0 + 1, hi), 0), H_MAX - 1);

    const float* img  = base + (size_t)c * img_stride;
    const float* row0 = img + (size_t)y0 * W_PAD;
    const float* row1 = img + (size_t)y1 * W_PAD;

    // ---- per-column taps: all indices first, then all 32 loads in flight ----
    float rx = w / w_res;                      // hoisted ratio (<=1.5ulp vs ref)
    int   x0a[8], x1a[8];
    float wxa[8];
#pragma unroll
    for (int j = 0; j < 8; ++j) {
        float xsf   = (float)(ox0 + j) + left;
        float src_x = fmaf(xsf + 0.5f, rx, -0.5f);
        src_x = fminf(fmaxf(src_x, 0.0f), w - 1.0f);
        float x0f = floorf(src_x);
        wxa[j] = src_x - x0f;
        int x0 = min(max(min(max((int)x0f, 0), wi), 0), W_MAX - 1);
        x1a[j] = min(max(min(x0 + 1, wi), 0), W_MAX - 1);
        x0a[j] = x0;
    }

    float v00[8], v01[8], v10[8], v11[8];
#pragma unroll
    for (int j = 0; j < 8; ++j) { v00[j] = row0[x0a[j]]; v01[j] = row0[x1a[j]]; }
#pragma unroll
    for (int j = 0; j < 8; ++j) { v10[j] = row1[x0a[j]]; v11[j] = row1[x1a[j]]; }

    float o[8];
#pragma unroll
    for (int j = 0; j < 8; ++j) {
        float lx0 = fmaf(wxa[j], v01[j] - v00[j], v00[j]);   // lerp row0
        float lx1 = fmaf(wxa[j], v11[j] - v10[j], v10[j]);   // lerp row1
        o[j] = fmaf(wy, lx1 - lx0, lx0);                     // lerp rows
    }

    size_t out_idx = ((size_t)((b * C_IMG + c) * OUT_H + oy)) * OUT_W + ox0;
    *(float4*)(out + out_idx)     = make_float4(o[0], o[1], o[2], o[3]);
    *(float4*)(out + out_idx + 4) = make_float4(o[4], o[5], o[6], o[7]);
}

extern "C" void kernel_launch(void* const* d_in, const int* in_sizes, int n_in,
                              void* d_out, int out_size, void* d_ws, size_t ws_size,
                              hipStream_t stream) {
    const float* x = (const float*)d_in[0];
    float* out = (float*)d_out;
    int total_octets = out_size / 8;           // 8 outputs per thread
    int block = 256;
    int grid = (total_octets + block - 1) / block;
    centercrop_kernel<<<grid, block, 0, stream>>>(x, out, total_octets);
}

// Round 5
// 264.092 us; speedup vs baseline: 1.0261x; 1.0261x over previous
//
#include <hip/hip_runtime.h>
#include <hip/hip_bf16.h>

#define C_IMG   3
#define H_MAX   512
#define W_MAX   512
#define W_PAD   513   // stored row stride (W_max + 1, last col holds h/w)
#define OUT_H   224
#define OUT_W   224
#define OW_Q    (OUT_W / 4)   // 56 quads per row
#define RESIZE_TO 256.0f

// 4 outputs/thread: best measured config (R3, 264.2us). 8/thread regressed
// (271us) — wider per-lane spans hurt intra-wave gather coalescing.
__global__ __launch_bounds__(256) void centercrop_kernel(
    const float* __restrict__ x, float* __restrict__ out, int total_quads)
{
    int idx = blockIdx.x * blockDim.x + threadIdx.x;
    if (idx >= total_quads) return;

    int q   = idx % OW_Q;          // which group of 4 output columns
    int t   = idx / OW_Q;
    int oy  = t % OUT_H;
    t      /= OUT_H;
    int c   = t % C_IMG;
    int b   = t / C_IMG;
    int ox0 = q * 4;

    const size_t img_stride = (size_t)H_MAX * W_PAD;       // per-channel elems
    const float* base = x + (size_t)b * C_IMG * img_stride;

    // h at [b,0,0,512], w at [b,1,0,512]
    float h = base[512];
    float w = base[img_stride + 512];

    float min_dim = fminf(h, w);
    float scale   = RESIZE_TO / min_dim;
    float h_res   = rintf(h * scale);          // jnp.round = half-even
    float w_res   = rintf(w * scale);
    float top     = rintf((h_res - (float)OUT_H) / 2.0f);
    float left    = rintf((w_res - (float)OUT_W) / 2.0f);

    // ---- per-row (computed once per thread, exact reference op order) ----
    float ysf   = (float)oy + top;
    float src_y = (ysf + 0.5f) * h / h_res - 0.5f;
    src_y = fminf(fmaxf(src_y, 0.0f), h - 1.0f);
    float y0f = floorf(src_y);
    float wy  = src_y - y0f;

    int hi = (int)h - 1;
    int wi = (int)w - 1;
    int y0 = min(max(min(max((int)y0f, 0), hi), 0), H_MAX - 1);
    int y1 = min(max(min(y0 + 1, hi), 0), H_MAX - 1);

    const float* img  = base + (size_t)c * img_stride;
    const float* row0 = img + (size_t)y0 * W_PAD;
    const float* row1 = img + (size_t)y1 * W_PAD;

    // ---- per-column taps: compute all indices first, then issue all loads ----
    float rx = w / w_res;                      // hoisted ratio (<=1.5ulp vs ref)
    int   x0a[4], x1a[4];
    float wxa[4];
#pragma unroll
    for (int j = 0; j < 4; ++j) {
        float xsf   = (float)(ox0 + j) + left;
        float src_x = fmaf(xsf + 0.5f, rx, -0.5f);
        src_x = fminf(fmaxf(src_x, 0.0f), w - 1.0f);
        float x0f = floorf(src_x);
        wxa[j] = src_x - x0f;
        int x0 = min(max(min(max((int)x0f, 0), wi), 0), W_MAX - 1);
        x1a[j] = min(max(min(x0 + 1, wi), 0), W_MAX - 1);
        x0a[j] = x0;
    }

    float v00[4], v01[4], v10[4], v11[4];
#pragma unroll
    for (int j = 0; j < 4; ++j) { v00[j] = row0[x0a[j]]; v01[j] = row0[x1a[j]]; }
#pragma unroll
    for (int j = 0; j < 4; ++j) { v10[j] = row1[x0a[j]]; v11[j] = row1[x1a[j]]; }

    float4 o;
    float* op = &o.x;
#pragma unroll
    for (int j = 0; j < 4; ++j) {
        float lx0 = fmaf(wxa[j], v01[j] - v00[j], v00[j]);   // lerp row0
        float lx1 = fmaf(wxa[j], v11[j] - v10[j], v10[j]);   // lerp row1
        op[j] = fmaf(wy, lx1 - lx0, lx0);                    // lerp rows
    }

    size_t out_idx = ((size_t)((b * C_IMG + c) * OUT_H + oy)) * OUT_W + ox0;
    *(float4*)(out + out_idx) = o;
}

extern "C" void kernel_launch(void* const* d_in, const int* in_sizes, int n_in,
                              void* d_out, int out_size, void* d_ws, size_t ws_size,
                              hipStream_t stream) {
    const float* x = (const float*)d_in[0];
    float* out = (float*)d_out;
    int total_quads = out_size / 4;            // 4 outputs per thread
    int block = 256;
    int grid = (total_quads + block - 1) / block;
    centercrop_kernel<<<grid, block, 0, stream>>>(x, out, total_quads);
}